// Round 3
// baseline (188.462 us; speedup 1.0000x reference)
//
#include <hip/hip_runtime.h>

#define F_SZ 32
#define D_SZ 128
#define FD   4096                 // F_SZ * D_SZ, elements per b-row of feature
#define NPAIR 496

typedef __bf16 bf16x8 __attribute__((ext_vector_type(8)));
typedef float floatx4 __attribute__((ext_vector_type(4)));

__device__ __forceinline__ unsigned short f2bf(float f) {
  unsigned u = __float_as_uint(f);
  u += 0x7fffu + ((u >> 16) & 1u);
  return (unsigned short)(u >> 16);
}

__device__ __forceinline__ void decode_pair(int p, int& io, int& jo) {
  int i = 0;
  while (p >= F_SZ - 1 - i) { p -= F_SZ - 1 - i; ++i; }
  io = i; jo = i + 1 + p;
}

// ---------------- Pass 1a: Zt[p][e][d] = bf16(gate(M[i][j][d][e])) ----------------
__global__ __launch_bounds__(256)
void prep_z(const float* __restrict__ mat, unsigned short* __restrict__ Zt) {
  __shared__ unsigned short tile[128 * 136];
  int i, j; decode_pair(blockIdx.x, i, j);
  const float* zp = mat + (((size_t)i * F_SZ + j) << 14);
  const int t = threadIdx.x;
  #pragma unroll 8
  for (int it = 0; it < 64; ++it) {
    int idx = it * 256 + t;            // e fastest -> coalesced global read
    int d = idx >> 7, e = idx & 127;
    float v = zp[idx];
    float s = 1.0f / (1.0f + __expf(-v));
    float z = fminf(1.0f, fmaxf(0.0f, fmaf(s, 1.2f, -0.1f)));
    tile[e * 136 + d] = f2bf(z);       // transposed store
  }
  __syncthreads();
  unsigned short* op = Zt + ((size_t)blockIdx.x << 14);
  #pragma unroll 4
  for (int it = 0; it < 16; ++it) {
    int idx4 = it * 256 + t;
    int e = idx4 >> 5, d4 = idx4 & 31;
    ushort4 v = *(const ushort4*)&tile[e * 136 + d4 * 4];
    *(ushort4*)&op[idx4 * 4] = v;
  }
}

// ---------------- Pass 1b: fb = bf16(feat), [B][F][D] ----------------
__global__ __launch_bounds__(256)
void prep_f(const float* __restrict__ feat, unsigned short* __restrict__ fb) {
  int gid = blockIdx.x * 256 + threadIdx.x;
  #pragma unroll
  for (int k = 0; k < 4; ++k) {
    size_t idx = (size_t)k * 262144 + gid;
    float4 v = *(const float4*)(feat + idx * 4);
    ushort4 h;
    h.x = f2bf(v.x); h.y = f2bf(v.y); h.z = f2bf(v.z); h.w = f2bf(v.w);
    *(ushort4*)(fb + idx * 4) = h;
  }
}

// ---------------- Pass 2: Yt-formulation pair GEMM, barrier-free ----------------
// Yt = Zt x(MFMA) fi^T : A = Zt rows (e x d, register-resident per block),
// B = fi rows (k=d, n=b) from bf16 fb. C-layout: col(lane&15)=b, row(quad*4+r)=e.
// Epilogue: out[b] += sum_e Yt[e,b]*fj[b,e] -- fj[b, mf*16+quad*4 + 0..3] is a
// float4 aligned with the 4 acc regs; reduce over quads with 2 shuffle stages;
// combine e-halves with global atomicAdd (out pre-zeroed). No __syncthreads.
__global__ __launch_bounds__(256, 2)
void pair_gemm(const unsigned short* __restrict__ Zt,
               const unsigned short* __restrict__ fb,
               const float* __restrict__ feat,
               float* __restrict__ out) {
  int i, j; decode_pair(blockIdx.x, i, j);
  const int t = threadIdx.x;
  const int lane = t & 63, l15 = lane & 15, quad = lane >> 4;
  const int wq = t >> 6, we = wq & 1, wb = wq >> 1;

  // A fragments: Zt rows e = we*64 + mf*16 + l15, d = ks*32 + quad*8 (+0..7).
  // 16 x dwordx4, once per block, register-resident.
  bf16x8 Afrag[4][4];
  {
    const unsigned short* zp = Zt + ((size_t)blockIdx.x << 14);
    #pragma unroll
    for (int mf = 0; mf < 4; ++mf) {
      const int e = we * 64 + mf * 16 + l15;
      #pragma unroll
      for (int ks = 0; ks < 4; ++ks)
        Afrag[mf][ks] = *(const bf16x8*)(zp + e * 128 + ks * 32 + quad * 8);
    }
  }

  const int bbase = blockIdx.y * 512;
  #pragma unroll 1
  for (int it = 0; it < 4; ++it) {
    const int rowbase = bbase + it * 128 + wb * 64;

    floatx4 acc[4][4];   // [mf(e)][nf(b)]
    #pragma unroll
    for (int mf = 0; mf < 4; ++mf)
      #pragma unroll
      for (int nf = 0; nf < 4; ++nf)
        acc[mf][nf] = (floatx4){0.f, 0.f, 0.f, 0.f};

    // Main GEMM: B = fi fragments straight from global bf16 (k=d contig dwordx4)
    #pragma unroll
    for (int ks = 0; ks < 4; ++ks) {
      bf16x8 Bf[4];
      #pragma unroll
      for (int nf = 0; nf < 4; ++nf)
        Bf[nf] = *(const bf16x8*)(fb + (size_t)(rowbase + nf * 16 + l15) * FD
                                     + i * D_SZ + ks * 32 + quad * 8);
      #pragma unroll
      for (int mf = 0; mf < 4; ++mf)
        #pragma unroll
        for (int nf = 0; nf < 4; ++nf)
          acc[mf][nf] = __builtin_amdgcn_mfma_f32_16x16x32_bf16(Afrag[mf][ks], Bf[nf], acc[mf][nf], 0, 0, 0);
    }

    // Epilogue: per nf, pl = sum over mf,r of Yt[e,b]*fj[b,e]; e = we*64+mf*16+quad*4+r
    #pragma unroll
    for (int nf = 0; nf < 4; ++nf) {
      const int b = rowbase + nf * 16 + l15;
      const float* fjp = feat + (size_t)b * FD + j * D_SZ + we * 64 + quad * 4;
      float4 fj0 = *(const float4*)(fjp);
      float4 fj1 = *(const float4*)(fjp + 16);
      float4 fj2 = *(const float4*)(fjp + 32);
      float4 fj3 = *(const float4*)(fjp + 48);
      float pl;
      {
        floatx4 c0 = acc[0][nf], c1 = acc[1][nf], c2 = acc[2][nf], c3 = acc[3][nf];
        pl  = c0[0] * fj0.x + c0[1] * fj0.y + c0[2] * fj0.z + c0[3] * fj0.w;
        pl += c1[0] * fj1.x + c1[1] * fj1.y + c1[2] * fj1.z + c1[3] * fj1.w;
        pl += c2[0] * fj2.x + c2[1] * fj2.y + c2[2] * fj2.z + c2[3] * fj2.w;
        pl += c3[0] * fj3.x + c3[1] * fj3.y + c3[2] * fj3.z + c3[3] * fj3.w;
      }
      // reduce over the 4 quads (e-groups): 2 butterfly stages
      pl += __shfl_xor(pl, 16, 64);
      pl += __shfl_xor(pl, 32, 64);
      if (quad == 0)
        atomicAdd(&out[(size_t)b * (F_SZ * F_SZ) + i * F_SZ + j], pl);
    }
  }
}

// ---------------- Fallback (round-1 kernel) if ws is too small ----------------
#define LDA  136
#define LDB  136

__global__ __launch_bounds__(256, 2)
void interaction_pair_kernel(const float* __restrict__ feat,
                             const float* __restrict__ mat,
                             float* __restrict__ out) {
  __shared__ unsigned short sA[128 * LDA];
  __shared__ unsigned short sBT[128 * LDB];
  const int t = threadIdx.x;
  const int w = t >> 6, lane = t & 63, l15 = lane & 15, quad = lane >> 4;
  int i, j; decode_pair(blockIdx.x, i, j);
  {
    const float* zp = mat + (((size_t)i * F_SZ + j) << 14);
    #pragma unroll 8
    for (int it = 0; it < 64; ++it) {
      int idx = it * 256 + t;
      int d = idx >> 7, e = idx & 127;
      float v = zp[idx];
      float s = 1.0f / (1.0f + __expf(-v));
      float z = fminf(1.0f, fmaxf(0.0f, fmaf(s, 1.2f, -0.1f)));
      sBT[e * LDB + d] = f2bf(z);
    }
  }
  for (int bt = 0; bt < 8; ++bt) {
    const int b0 = bt * 128;
    #pragma unroll 4
    for (int it = 0; it < 16; ++it) {
      int idx4 = it * 256 + t;
      int r = idx4 >> 5, c4 = idx4 & 31;
      const float4 v = *(const float4*)(feat + (size_t)(b0 + r) * FD + i * D_SZ + c4 * 4);
      ushort4 h;
      h.x = f2bf(v.x); h.y = f2bf(v.y); h.z = f2bf(v.z); h.w = f2bf(v.w);
      *(ushort4*)(&sA[r * LDA + c4 * 4]) = h;
    }
    __syncthreads();
    floatx4 acc[2][8];
    #pragma unroll
    for (int mf = 0; mf < 2; ++mf)
      #pragma unroll
      for (int nf = 0; nf < 8; ++nf)
        acc[mf][nf] = (floatx4){0.f, 0.f, 0.f, 0.f};
    #pragma unroll
    for (int k0 = 0; k0 < 128; k0 += 32) {
      const int kc = k0 + quad * 8;
      bf16x8 a0 = *(const bf16x8*)&sA[(w * 32 +      l15) * LDA + kc];
      bf16x8 a1 = *(const bf16x8*)&sA[(w * 32 + 16 + l15) * LDA + kc];
      #pragma unroll
      for (int nf = 0; nf < 8; ++nf) {
        bf16x8 bfr = *(const bf16x8*)&sBT[(nf * 16 + l15) * LDB + kc];
        acc[0][nf] = __builtin_amdgcn_mfma_f32_16x16x32_bf16(a0, bfr, acc[0][nf], 0, 0, 0);
        acc[1][nf] = __builtin_amdgcn_mfma_f32_16x16x32_bf16(a1, bfr, acc[1][nf], 0, 0, 0);
      }
    }
    #pragma unroll
    for (int mf = 0; mf < 2; ++mf) {
      float pl[4] = {0.f, 0.f, 0.f, 0.f};
      const int rb = w * 32 + mf * 16 + quad * 4;
      #pragma unroll
      for (int nf = 0; nf < 8; ++nf) {
        const int col = nf * 16 + l15;
        const float* fj = feat + (size_t)(b0 + rb) * FD + j * D_SZ + col;
        floatx4 c = acc[mf][nf];
        pl[0] += c[0] * fj[0];
        pl[1] += c[1] * fj[FD];
        pl[2] += c[2] * fj[2 * FD];
        pl[3] += c[3] * fj[3 * FD];
      }
      #pragma unroll
      for (int off = 1; off < 16; off <<= 1) {
        pl[0] += __shfl_xor(pl[0], off, 64);
        pl[1] += __shfl_xor(pl[1], off, 64);
        pl[2] += __shfl_xor(pl[2], off, 64);
        pl[3] += __shfl_xor(pl[3], off, 64);
      }
      if (l15 == 0) {
        size_t ob = (size_t)(b0 + rb) * (F_SZ * F_SZ) + (size_t)i * F_SZ + j;
        out[ob]                   = pl[0];
        out[ob + 1 * F_SZ * F_SZ] = pl[1];
        out[ob + 2 * F_SZ * F_SZ] = pl[2];
        out[ob + 3 * F_SZ * F_SZ] = pl[3];
      }
    }
    __syncthreads();
  }
}

extern "C" void kernel_launch(void* const* d_in, const int* in_sizes, int n_in,
                              void* d_out, int out_size, void* d_ws, size_t ws_size,
                              hipStream_t stream) {
  const float* feat = (const float*)d_in[0];   // [B, F, D] fp32
  const float* mat  = (const float*)d_in[1];   // [F, F, D, D] fp32
  float* out = (float*)d_out;                  // [B, F, F] fp32

  hipMemsetAsync(out, 0, (size_t)out_size * sizeof(float), stream);

  const size_t zt_bytes = (size_t)NPAIR * D_SZ * D_SZ * sizeof(unsigned short);
  const size_t fb_bytes = (size_t)1024 * FD * sizeof(unsigned short);

  if (ws_size >= zt_bytes + fb_bytes) {
    unsigned short* Zt = (unsigned short*)d_ws;
    unsigned short* fbuf = Zt + (size_t)NPAIR * D_SZ * D_SZ;
    prep_z<<<dim3(NPAIR), dim3(256), 0, stream>>>(mat, Zt);
    prep_f<<<dim3(1024), dim3(256), 0, stream>>>(feat, fbuf);
    pair_gemm<<<dim3(NPAIR, 2), dim3(256), 0, stream>>>(Zt, fbuf, feat, out);
  } else {
    interaction_pair_kernel<<<dim3(NPAIR), dim3(256), 0, stream>>>(feat, mat, out);
  }
}

// Round 4
// 160.913 us; speedup vs baseline: 1.1712x; 1.1712x over previous
//
#include <hip/hip_runtime.h>

#define F_SZ 32
#define D_SZ 128
#define FD   4096                 // F_SZ * D_SZ
#define NPAIR 496
#define LDZ  136                  // padded LDS row stride in shorts (272B = 17*16B: aligned, 2-way banks)

typedef __bf16 bf16x8 __attribute__((ext_vector_type(8)));
typedef float floatx4 __attribute__((ext_vector_type(4)));

__device__ __forceinline__ unsigned short f2bf(float f) {
  unsigned u = __float_as_uint(f);
  u += 0x7fffu + ((u >> 16) & 1u);
  return (unsigned short)(u >> 16);
}
__device__ __forceinline__ float bf2f(unsigned short h) {
  return __uint_as_float(((unsigned)h) << 16);
}
__device__ __forceinline__ void decode_pair(int p, int& io, int& jo) {
  int i = 0;
  while (p >= F_SZ - 1 - i) { p -= F_SZ - 1 - i; ++i; }
  io = i; jo = i + 1 + p;
}

// ---------------- Pass 1 (merged): Zt[p][e][d] = bf16(gate(M[i][j][d][e])), fb = bf16(feat) ----------------
__global__ __launch_bounds__(256)
void prep(const float* __restrict__ mat, const float* __restrict__ feat,
          unsigned short* __restrict__ Zt, unsigned short* __restrict__ fb) {
  const int t = threadIdx.x;
  if (blockIdx.x < NPAIR) {
    __shared__ unsigned short tile[128 * LDZ];
    int i, j; decode_pair(blockIdx.x, i, j);
    const float* zp = mat + (((size_t)i * F_SZ + j) << 14);
    #pragma unroll 8
    for (int it = 0; it < 64; ++it) {
      int idx = it * 256 + t;          // d-major read: e fastest -> coalesced
      int d = idx >> 7, e = idx & 127;
      float v = zp[idx];
      float s = 1.0f / (1.0f + __expf(-v));
      float z = fminf(1.0f, fmaxf(0.0f, fmaf(s, 1.2f, -0.1f)));
      tile[e * LDZ + d] = f2bf(z);     // transposed store
    }
    __syncthreads();
    unsigned short* op = Zt + ((size_t)blockIdx.x << 14);
    #pragma unroll 4
    for (int it = 0; it < 16; ++it) {
      int idx4 = it * 256 + t;         // 4096 ushort4 groups
      int e = idx4 >> 5, d4 = idx4 & 31;
      *(ushort4*)&op[idx4 * 4] = *(const ushort4*)&tile[e * LDZ + d4 * 4];
    }
  } else {
    const int blk = blockIdx.x - NPAIR;      // 0..255
    #pragma unroll 4
    for (int k = 0; k < 16; ++k) {
      size_t v4 = (size_t)blk * 4096 + k * 256 + t;   // float4 index, 1,048,576 total
      float4 v = ((const float4*)feat)[v4];
      ushort4 h;
      h.x = f2bf(v.x); h.y = f2bf(v.y); h.z = f2bf(v.z); h.w = f2bf(v.w);
      *(ushort4*)(fb + v4 * 4) = h;
    }
  }
}

// ---------------- Pass 2: one block per (pair, 128-b tile) ----------------
// Yt = Zt x(MFMA) fi^T. A = Zt rows [e][d] staged in padded LDS (read once from
// global per block); B = fi rows (k=d) direct from bf16 fb. Wave tile 32b x 128e
// (full e) -> no cross-wave combine, no atomics, single barrier.
// C-layout (verified r1-r3): col(lane&15)=b, row(quad*4+reg)=e.
__global__ __launch_bounds__(256, 3)
void pair_gemm(const unsigned short* __restrict__ Zt,
               const unsigned short* __restrict__ fb,
               float* __restrict__ out) {
  __shared__ unsigned short sZ[128 * LDZ];
  int i, j; decode_pair(blockIdx.x, i, j);
  const int t = threadIdx.x;
  const int lane = t & 63, l15 = lane & 15, quad = lane >> 4;
  const int w = t >> 6;
  const int rowbase = blockIdx.y * 128 + w * 32;

  // ---- stage Zt tile (32KB) into padded LDS: coalesced 16B loads + 16B LDS stores ----
  {
    const unsigned short* zp = Zt + ((size_t)blockIdx.x << 14);
    #pragma unroll
    for (int r = 0; r < 8; ++r) {
      int s = r * 256 + t;             // 16B-chunk slot 0..2047
      int row = s >> 4, c = s & 15;
      uint4 v = *(const uint4*)(zp + s * 8);
      *(uint4*)&sZ[row * LDZ + c * 8] = v;
    }
  }

  floatx4 acc[8][2];
  #pragma unroll
  for (int mf = 0; mf < 8; ++mf) {
    acc[mf][0] = (floatx4){0.f, 0.f, 0.f, 0.f};
    acc[mf][1] = (floatx4){0.f, 0.f, 0.f, 0.f};
  }
  __syncthreads();

  // ---- main: 64 MFMAs/wave, A streamed from LDS (each frag feeds 2 MFMAs) ----
  const unsigned short* fbp0 = fb + (size_t)(rowbase + l15) * FD + i * D_SZ + quad * 8;
  const unsigned short* fbp1 = fbp0 + 16 * FD;
  #pragma unroll
  for (int ks = 0; ks < 4; ++ks) {
    bf16x8 B0 = *(const bf16x8*)(fbp0 + ks * 32);
    bf16x8 B1 = *(const bf16x8*)(fbp1 + ks * 32);
    #pragma unroll
    for (int mf = 0; mf < 8; ++mf) {
      bf16x8 A = *(const bf16x8*)&sZ[(mf * 16 + l15) * LDZ + ks * 32 + quad * 8];
      acc[mf][0] = __builtin_amdgcn_mfma_f32_16x16x32_bf16(A, B0, acc[mf][0], 0, 0, 0);
      acc[mf][1] = __builtin_amdgcn_mfma_f32_16x16x32_bf16(A, B1, acc[mf][1], 0, 0, 0);
    }
  }

  // ---- epilogue: out[b,i,j] = sum_e Yt[e,b] * fj[b,e]; e = mf*16 + quad*4 + r ----
  #pragma unroll
  for (int nf = 0; nf < 2; ++nf) {
    const int b = rowbase + nf * 16 + l15;
    const unsigned short* fjp = fb + (size_t)b * FD + j * D_SZ + quad * 4;
    float pl = 0.f;
    #pragma unroll
    for (int mf = 0; mf < 8; ++mf) {
      ushort4 fh = *(const ushort4*)(fjp + mf * 16);
      floatx4 c = acc[mf][nf];
      pl = fmaf(c[0], bf2f(fh.x), pl);
      pl = fmaf(c[1], bf2f(fh.y), pl);
      pl = fmaf(c[2], bf2f(fh.z), pl);
      pl = fmaf(c[3], bf2f(fh.w), pl);
    }
    pl += __shfl_xor(pl, 16, 64);
    pl += __shfl_xor(pl, 32, 64);
    if (quad == 0)
      out[(size_t)b * (F_SZ * F_SZ) + i * F_SZ + j] = pl;
  }
}

// ---------------- Fallback (round-1 kernel) if ws is too small ----------------
#define LDA  136
#define LDB  136
__global__ __launch_bounds__(256, 2)
void interaction_pair_kernel(const float* __restrict__ feat,
                             const float* __restrict__ mat,
                             float* __restrict__ out) {
  __shared__ unsigned short sA[128 * LDA];
  __shared__ unsigned short sBT[128 * LDB];
  const int t = threadIdx.x;
  const int w = t >> 6, lane = t & 63, l15 = lane & 15, quad = lane >> 4;
  int i, j; decode_pair(blockIdx.x, i, j);
  {
    const float* zp = mat + (((size_t)i * F_SZ + j) << 14);
    #pragma unroll 8
    for (int it = 0; it < 64; ++it) {
      int idx = it * 256 + t;
      int d = idx >> 7, e = idx & 127;
      float v = zp[idx];
      float s = 1.0f / (1.0f + __expf(-v));
      float z = fminf(1.0f, fmaxf(0.0f, fmaf(s, 1.2f, -0.1f)));
      sBT[e * LDB + d] = f2bf(z);
    }
  }
  for (int bt = 0; bt < 8; ++bt) {
    const int b0 = bt * 128;
    #pragma unroll 4
    for (int it = 0; it < 16; ++it) {
      int idx4 = it * 256 + t;
      int r = idx4 >> 5, c4 = idx4 & 31;
      const float4 v = *(const float4*)(feat + (size_t)(b0 + r) * FD + i * D_SZ + c4 * 4);
      ushort4 h;
      h.x = f2bf(v.x); h.y = f2bf(v.y); h.z = f2bf(v.z); h.w = f2bf(v.w);
      *(ushort4*)(&sA[r * LDA + c4 * 4]) = h;
    }
    __syncthreads();
    floatx4 acc[2][8];
    #pragma unroll
    for (int mf = 0; mf < 2; ++mf)
      #pragma unroll
      for (int nf = 0; nf < 8; ++nf)
        acc[mf][nf] = (floatx4){0.f, 0.f, 0.f, 0.f};
    #pragma unroll
    for (int k0 = 0; k0 < 128; k0 += 32) {
      const int kc = k0 + quad * 8;
      bf16x8 a0 = *(const bf16x8*)&sA[(w * 32 +      l15) * LDA + kc];
      bf16x8 a1 = *(const bf16x8*)&sA[(w * 32 + 16 + l15) * LDA + kc];
      #pragma unroll
      for (int nf = 0; nf < 8; ++nf) {
        bf16x8 bfr = *(const bf16x8*)&sBT[(nf * 16 + l15) * LDB + kc];
        acc[0][nf] = __builtin_amdgcn_mfma_f32_16x16x32_bf16(a0, bfr, acc[0][nf], 0, 0, 0);
        acc[1][nf] = __builtin_amdgcn_mfma_f32_16x16x32_bf16(a1, bfr, acc[1][nf], 0, 0, 0);
      }
    }
    #pragma unroll
    for (int mf = 0; mf < 2; ++mf) {
      float pl[4] = {0.f, 0.f, 0.f, 0.f};
      const int rb = w * 32 + mf * 16 + quad * 4;
      #pragma unroll
      for (int nf = 0; nf < 8; ++nf) {
        const int col = nf * 16 + l15;
        const float* fj = feat + (size_t)(b0 + rb) * FD + j * D_SZ + col;
        floatx4 c = acc[mf][nf];
        pl[0] += c[0] * fj[0];
        pl[1] += c[1] * fj[FD];
        pl[2] += c[2] * fj[2 * FD];
        pl[3] += c[3] * fj[3 * FD];
      }
      #pragma unroll
      for (int off = 1; off < 16; off <<= 1) {
        pl[0] += __shfl_xor(pl[0], off, 64);
        pl[1] += __shfl_xor(pl[1], off, 64);
        pl[2] += __shfl_xor(pl[2], off, 64);
        pl[3] += __shfl_xor(pl[3], off, 64);
      }
      if (l15 == 0) {
        size_t ob = (size_t)(b0 + rb) * (F_SZ * F_SZ) + (size_t)i * F_SZ + j;
        out[ob]                   = pl[0];
        out[ob + 1 * F_SZ * F_SZ] = pl[1];
        out[ob + 2 * F_SZ * F_SZ] = pl[2];
        out[ob + 3 * F_SZ * F_SZ] = pl[3];
      }
    }
    __syncthreads();
  }
}

extern "C" void kernel_launch(void* const* d_in, const int* in_sizes, int n_in,
                              void* d_out, int out_size, void* d_ws, size_t ws_size,
                              hipStream_t stream) {
  const float* feat = (const float*)d_in[0];   // [B, F, D] fp32
  const float* mat  = (const float*)d_in[1];   // [F, F, D, D] fp32
  float* out = (float*)d_out;                  // [B, F, F] fp32

  hipMemsetAsync(out, 0, (size_t)out_size * sizeof(float), stream);

  const size_t zt_bytes = (size_t)NPAIR * D_SZ * D_SZ * sizeof(unsigned short);
  const size_t fb_bytes = (size_t)1024 * FD * sizeof(unsigned short);

  if (ws_size >= zt_bytes + fb_bytes) {
    unsigned short* Zt = (unsigned short*)d_ws;
    unsigned short* fbuf = Zt + (size_t)NPAIR * D_SZ * D_SZ;
    prep<<<dim3(NPAIR + 256), dim3(256), 0, stream>>>(mat, feat, Zt, fbuf);
    pair_gemm<<<dim3(NPAIR, 8), dim3(256), 0, stream>>>(Zt, fbuf, out);
  } else {
    interaction_pair_kernel<<<dim3(NPAIR), dim3(256), 0, stream>>>(feat, mat, out);
  }
}

// Round 5
// 158.030 us; speedup vs baseline: 1.1926x; 1.0182x over previous
//
#include <hip/hip_runtime.h>

#define F_SZ 32
#define D_SZ 128
#define FD   4096                 // F_SZ * D_SZ
#define NPAIR 496
#define LDZ  136                  // padded LDS row stride (shorts); 272B rows keep b128 reads aligned, ~conflict-free

typedef __bf16 bf16x8 __attribute__((ext_vector_type(8)));
typedef float floatx4 __attribute__((ext_vector_type(4)));

__device__ __forceinline__ unsigned short f2bf(float f) {
  unsigned u = __float_as_uint(f);
  u += 0x7fffu + ((u >> 16) & 1u);
  return (unsigned short)(u >> 16);
}
__device__ __forceinline__ float bf2f(unsigned short h) {
  return __uint_as_float(((unsigned)h) << 16);
}
__device__ __forceinline__ void decode_pair(int p, int& io, int& jo) {
  int i = 0;
  while (p >= F_SZ - 1 - i) { p -= F_SZ - 1 - i; ++i; }
  io = i; jo = i + 1 + p;
}

// ---------------- Pass 1: fb = bf16(feat), [B][F][D] ----------------
__global__ __launch_bounds__(256)
void prep_f(const float* __restrict__ feat, unsigned short* __restrict__ fb) {
  const int t = threadIdx.x;
  const int blk = blockIdx.x;            // 0..255
  #pragma unroll 4
  for (int k = 0; k < 16; ++k) {
    size_t v4 = (size_t)blk * 4096 + k * 256 + t;   // float4 index, 1,048,576 total
    float4 v = ((const float4*)feat)[v4];
    ushort4 h;
    h.x = f2bf(v.x); h.y = f2bf(v.y); h.z = f2bf(v.z); h.w = f2bf(v.w);
    *(ushort4*)(fb + v4 * 4) = h;
  }
}

// ---------------- Pass 2: fused gate + GEMM + row-dot ----------------
// grid (496 pairs, 2 b-halves). Per block:
//   1. read pair's 64KB fp32 mat tile (coalesced), gate -> bf16 -> LDS transposed [e][d]
//   2. each wave pulls the WHOLE Zt tile into registers: A[8][4] bf16x8 (128 VGPRs)
//   3. 4 iterations over 128-b tiles: Yt = A x(MFMA) fi^T, B from bf16 fb (dwordx4),
//      epilogue dot vs bf16 fj + 2 butterfly stages. No barriers/LDS after step 2.
// C/D layout (verified r1-r4): col(lane&15)=b, row(quad*4+reg)=e.
__global__ __launch_bounds__(256, 2)
void pair_gemm(const float* __restrict__ mat,
               const unsigned short* __restrict__ fb,
               float* __restrict__ out) {
  __shared__ unsigned short sZ[128 * LDZ];
  int i, j; decode_pair(blockIdx.x, i, j);
  const int t = threadIdx.x;
  const int lane = t & 63, l15 = lane & 15, quad = lane >> 4;
  const int w = t >> 6;

  // ---- stage: gate(mat) -> sZ[e][d] (r1-verified transpose pattern) ----
  {
    const float* zp = mat + (((size_t)i * F_SZ + j) << 14);
    #pragma unroll 8
    for (int it = 0; it < 64; ++it) {
      int idx = it * 256 + t;          // d-major: e fastest -> coalesced dword reads
      int d = idx >> 7, e = idx & 127;
      float v = zp[idx];
      float s = 1.0f / (1.0f + __expf(-v));
      float z = fminf(1.0f, fmaxf(0.0f, fmaf(s, 1.2f, -0.1f)));
      sZ[e * LDZ + d] = f2bf(z);       // transposed store
    }
  }
  __syncthreads();

  // ---- A fragments: full 128e x 128d, register-resident (32 ds_read_b128) ----
  bf16x8 A[8][4];
  #pragma unroll
  for (int mf = 0; mf < 8; ++mf)
    #pragma unroll
    for (int ks = 0; ks < 4; ++ks)
      A[mf][ks] = *(const bf16x8*)&sZ[(mf * 16 + l15) * LDZ + ks * 32 + quad * 8];

  const int bhalf = blockIdx.y * 512;

  #pragma unroll 2
  for (int itb = 0; itb < 4; ++itb) {
    const int rowbase = bhalf + itb * 128 + w * 32;

    // B (fi) fragments straight from global bf16: k=d contiguous dwordx4
    const unsigned short* fbp0 = fb + (size_t)(rowbase + l15) * FD + i * D_SZ + quad * 8;
    bf16x8 B0[4], B1[4];
    #pragma unroll
    for (int ks = 0; ks < 4; ++ks) {
      B0[ks] = *(const bf16x8*)(fbp0 + ks * 32);
      B1[ks] = *(const bf16x8*)(fbp0 + 16 * FD + ks * 32);
    }

    floatx4 acc[8][2];
    #pragma unroll
    for (int mf = 0; mf < 8; ++mf) {
      acc[mf][0] = (floatx4){0.f, 0.f, 0.f, 0.f};
      acc[mf][1] = (floatx4){0.f, 0.f, 0.f, 0.f};
    }

    #pragma unroll
    for (int ks = 0; ks < 4; ++ks)
      #pragma unroll
      for (int mf = 0; mf < 8; ++mf) {
        acc[mf][0] = __builtin_amdgcn_mfma_f32_16x16x32_bf16(A[mf][ks], B0[ks], acc[mf][0], 0, 0, 0);
        acc[mf][1] = __builtin_amdgcn_mfma_f32_16x16x32_bf16(A[mf][ks], B1[ks], acc[mf][1], 0, 0, 0);
      }

    // epilogue: out[b,i,j] = sum_e Yt[e,b]*fj[b,e]; e = mf*16 + quad*4 + r
    #pragma unroll
    for (int nf = 0; nf < 2; ++nf) {
      const int b = rowbase + nf * 16 + l15;
      const unsigned short* fjp = fb + (size_t)b * FD + j * D_SZ + quad * 4;
      float pl = 0.f;
      #pragma unroll
      for (int mf = 0; mf < 8; ++mf) {
        ushort4 fh = *(const ushort4*)(fjp + mf * 16);
        floatx4 c = acc[mf][nf];
        pl = fmaf(c[0], bf2f(fh.x), pl);
        pl = fmaf(c[1], bf2f(fh.y), pl);
        pl = fmaf(c[2], bf2f(fh.z), pl);
        pl = fmaf(c[3], bf2f(fh.w), pl);
      }
      pl += __shfl_xor(pl, 16, 64);
      pl += __shfl_xor(pl, 32, 64);
      if (quad == 0)
        out[(size_t)b * (F_SZ * F_SZ) + i * F_SZ + j] = pl;
    }
  }
}

// ---------------- Fallback (round-1 kernel, needs no workspace) ----------------
#define LDA  136
#define LDB  136
__global__ __launch_bounds__(256, 2)
void interaction_pair_kernel(const float* __restrict__ feat,
                             const float* __restrict__ mat,
                             float* __restrict__ out) {
  __shared__ unsigned short sA[128 * LDA];
  __shared__ unsigned short sBT[128 * LDB];
  const int t = threadIdx.x;
  const int w = t >> 6, lane = t & 63, l15 = lane & 15, quad = lane >> 4;
  int i, j; decode_pair(blockIdx.x, i, j);
  {
    const float* zp = mat + (((size_t)i * F_SZ + j) << 14);
    #pragma unroll 8
    for (int it = 0; it < 64; ++it) {
      int idx = it * 256 + t;
      int d = idx >> 7, e = idx & 127;
      float v = zp[idx];
      float s = 1.0f / (1.0f + __expf(-v));
      float z = fminf(1.0f, fmaxf(0.0f, fmaf(s, 1.2f, -0.1f)));
      sBT[e * LDB + d] = f2bf(z);
    }
  }
  for (int bt = 0; bt < 8; ++bt) {
    const int b0 = bt * 128;
    #pragma unroll 4
    for (int it = 0; it < 16; ++it) {
      int idx4 = it * 256 + t;
      int r = idx4 >> 5, c4 = idx4 & 31;
      const float4 v = *(const float4*)(feat + (size_t)(b0 + r) * FD + i * D_SZ + c4 * 4);
      ushort4 h;
      h.x = f2bf(v.x); h.y = f2bf(v.y); h.z = f2bf(v.z); h.w = f2bf(v.w);
      *(ushort4*)(&sA[r * LDA + c4 * 4]) = h;
    }
    __syncthreads();
    floatx4 acc[2][8];
    #pragma unroll
    for (int mf = 0; mf < 2; ++mf)
      #pragma unroll
      for (int nf = 0; nf < 8; ++nf)
        acc[mf][nf] = (floatx4){0.f, 0.f, 0.f, 0.f};
    #pragma unroll
    for (int k0 = 0; k0 < 128; k0 += 32) {
      const int kc = k0 + quad * 8;
      bf16x8 a0 = *(const bf16x8*)&sA[(w * 32 +      l15) * LDA + kc];
      bf16x8 a1 = *(const bf16x8*)&sA[(w * 32 + 16 + l15) * LDA + kc];
      #pragma unroll
      for (int nf = 0; nf < 8; ++nf) {
        bf16x8 bfr = *(const bf16x8*)&sBT[(nf * 16 + l15) * LDB + kc];
        acc[0][nf] = __builtin_amdgcn_mfma_f32_16x16x32_bf16(a0, bfr, acc[0][nf], 0, 0, 0);
        acc[1][nf] = __builtin_amdgcn_mfma_f32_16x16x32_bf16(a1, bfr, acc[1][nf], 0, 0, 0);
      }
    }
    #pragma unroll
    for (int mf = 0; mf < 2; ++mf) {
      float pl[4] = {0.f, 0.f, 0.f, 0.f};
      const int rb = w * 32 + mf * 16 + quad * 4;
      #pragma unroll
      for (int nf = 0; nf < 8; ++nf) {
        const int col = nf * 16 + l15;
        const float* fj = feat + (size_t)(b0 + rb) * FD + j * D_SZ + col;
        floatx4 c = acc[mf][nf];
        pl[0] += c[0] * fj[0];
        pl[1] += c[1] * fj[FD];
        pl[2] += c[2] * fj[2 * FD];
        pl[3] += c[3] * fj[3 * FD];
      }
      #pragma unroll
      for (int off = 1; off < 16; off <<= 1) {
        pl[0] += __shfl_xor(pl[0], off, 64);
        pl[1] += __shfl_xor(pl[1], off, 64);
        pl[2] += __shfl_xor(pl[2], off, 64);
        pl[3] += __shfl_xor(pl[3], off, 64);
      }
      if (l15 == 0) {
        size_t ob = (size_t)(b0 + rb) * (F_SZ * F_SZ) + (size_t)i * F_SZ + j;
        out[ob]                   = pl[0];
        out[ob + 1 * F_SZ * F_SZ] = pl[1];
        out[ob + 2 * F_SZ * F_SZ] = pl[2];
        out[ob + 3 * F_SZ * F_SZ] = pl[3];
      }
    }
    __syncthreads();
  }
}

extern "C" void kernel_launch(void* const* d_in, const int* in_sizes, int n_in,
                              void* d_out, int out_size, void* d_ws, size_t ws_size,
                              hipStream_t stream) {
  const float* feat = (const float*)d_in[0];   // [B, F, D] fp32
  const float* mat  = (const float*)d_in[1];   // [F, F, D, D] fp32
  float* out = (float*)d_out;                  // [B, F, F] fp32

  hipMemsetAsync(out, 0, (size_t)out_size * sizeof(float), stream);

  const size_t fb_bytes = (size_t)1024 * FD * sizeof(unsigned short);   // 8 MB

  if (ws_size >= fb_bytes) {
    unsigned short* fbuf = (unsigned short*)d_ws;
    prep_f<<<dim3(256), dim3(256), 0, stream>>>(feat, fbuf);
    pair_gemm<<<dim3(NPAIR, 2), dim3(256), 0, stream>>>(mat, fbuf, out);
  } else {
    interaction_pair_kernel<<<dim3(NPAIR), dim3(256), 0, stream>>>(feat, mat, out);
  }
}